// Round 3
// baseline (228.653 us; speedup 1.0000x reference)
//
#include <hip/hip_runtime.h>
#include <hip/hip_cooperative_groups.h>
#include <math.h>

namespace cg = cooperative_groups;

#define NN 4096
#define NE 131072
#define C 128
#define NH 8
#define HD 16
#define NBLK 512
#define NPB 8          // nodes per block (phases 1/3)
#define LCAP 1024      // per-wave neighbor-list capacity (expected deg ~32, max ~70)
#define SCAP 256       // per-wave cached-score capacity (floats per head)

__device__ __forceinline__ float dot16(const float* __restrict__ q, const float* __restrict__ kp) {
    const float4* k4 = reinterpret_cast<const float4*>(kp);
    const float4 k0 = k4[0], k1 = k4[1], k2 = k4[2], k3 = k4[3];
    return q[0]*k0.x + q[1]*k0.y + q[2]*k0.z + q[3]*k0.w
         + q[4]*k1.x + q[5]*k1.y + q[6]*k1.z + q[7]*k1.w
         + q[8]*k2.x + q[9]*k2.y + q[10]*k2.z + q[11]*k2.w
         + q[12]*k3.x + q[13]*k3.y + q[14]*k3.z + q[15]*k3.w;
}

__device__ __forceinline__ void pv16(float p, const float* __restrict__ vp, float* __restrict__ acc) {
    const float4* v4 = reinterpret_cast<const float4*>(vp);
    const float4 v0 = v4[0], v1 = v4[1], v2 = v4[2], v3 = v4[3];
    acc[0]  = fmaf(p, v0.x, acc[0]);  acc[1]  = fmaf(p, v0.y, acc[1]);
    acc[2]  = fmaf(p, v0.z, acc[2]);  acc[3]  = fmaf(p, v0.w, acc[3]);
    acc[4]  = fmaf(p, v1.x, acc[4]);  acc[5]  = fmaf(p, v1.y, acc[5]);
    acc[6]  = fmaf(p, v1.z, acc[6]);  acc[7]  = fmaf(p, v1.w, acc[7]);
    acc[8]  = fmaf(p, v2.x, acc[8]);  acc[9]  = fmaf(p, v2.y, acc[9]);
    acc[10] = fmaf(p, v2.z, acc[10]); acc[11] = fmaf(p, v2.w, acc[11]);
    acc[12] = fmaf(p, v3.x, acc[12]); acc[13] = fmaf(p, v3.y, acc[13]);
    acc[14] = fmaf(p, v3.z, acc[14]); acc[15] = fmaf(p, v3.w, acc[15]);
}

union SharedU {
    float xs[NPB][C];                                   // phases 1/3: 4 KiB
    struct {                                            // phase 2: 8 + 32 KiB
        unsigned short nb[4][LCAP];
        float sc[4][SCAP * NH];
    } c;
};

__global__ __launch_bounds__(256, 2) void gat_fused(
    const float* __restrict__ x, const int* __restrict__ ei,
    const float* __restrict__ Wq, const float* __restrict__ bq,
    const float* __restrict__ Wk, const float* __restrict__ bk,
    const float* __restrict__ Wv, const float* __restrict__ bv,
    const float* __restrict__ Wo, const float* __restrict__ bo,
    char* __restrict__ ws, float* __restrict__ out)
{
    float* Q    = (float*)ws;
    float* K    = Q + NN * C;
    float* V    = K + NN * C;
    float* attn = V + NN * C;
    unsigned int* mask = (unsigned int*)(attn + NN * C);   // 2 MiB bitmask

    __shared__ SharedU sh;

    const int tid = threadIdx.x;
    const int blk = blockIdx.x;
    cg::grid_group grid = cg::this_grid();

    // ---------------- phase 0: clear adjacency bitmask ----------------
    {
        float4* mc = (float4*)mask;          // 131072 float4 == 512*256 threads
        mc[blk * 256 + tid] = make_float4(0.f, 0.f, 0.f, 0.f);
    }
    grid.sync();

    // ---------------- phase 1: edge scatter + QKV projection ----------------
    {
        // one edge per thread (atomics overlap the FMA loop below)
        const int e = blk * 256 + tid;
        int src = ei[e];
        int dst = ei[NE + e];
        src = src < 0 ? 0 : (src > NN - 1 ? NN - 1 : src);
        dst = dst < 0 ? 0 : (dst > NN - 1 ? NN - 1 : dst);
        atomicOr(&mask[(src << 7) + (dst >> 5)], 1u << (dst & 31));

        const int n0 = blk * NPB;
        for (int i = tid; i < NPB * C; i += 256)
            sh.xs[i >> 7][i & 127] = x[n0 * C + i];
        __syncthreads();

        const int c = tid & 127;
        const int half = tid >> 7;           // handles nodes half*4 .. +4
        float aq[4], ak[4], av[4];
        #pragma unroll
        for (int j = 0; j < 4; j++) { aq[j] = 0.f; ak[j] = 0.f; av[j] = 0.f; }
        for (int k = 0; k < C; k++) {
            const float wq = Wq[k * C + c];
            const float wk = Wk[k * C + c];
            const float wv = Wv[k * C + c];
            #pragma unroll
            for (int j = 0; j < 4; j++) {
                const float xv = sh.xs[half * 4 + j][k];
                aq[j] = fmaf(xv, wq, aq[j]);
                ak[j] = fmaf(xv, wk, ak[j]);
                av[j] = fmaf(xv, wv, av[j]);
            }
        }
        const float bqv = bq[c], bkv = bk[c], bvv = bv[c];
        #pragma unroll
        for (int j = 0; j < 4; j++) {
            const int n = n0 + half * 4 + j;
            Q[n * C + c] = aq[j] + bqv;
            K[n * C + c] = ak[j] + bkv;
            V[n * C + c] = av[j] + bvv;
        }
    }
    grid.sync();

    // ---------------- phase 2: sparse attention, one wave per node ----------------
    {
        const int w = tid >> 6;
        const int lane = tid & 63;
        unsigned short* nb = sh.c.nb[w];
        float* sc = sh.c.sc[w];
        const int h = lane & 7;              // head
        const int sub = lane >> 3;           // 8 sub-lanes per head

        for (int rep = 0; rep < 2; rep++) {
            const int n = blk * NPB + w * 2 + rep;
            const unsigned int* row = mask + n * (NN / 32);
            unsigned int b0 = row[lane * 2];
            unsigned int b1 = row[lane * 2 + 1];
            const int myc = __popc(b0) + __popc(b1);
            int incl = myc;
            #pragma unroll
            for (int d = 1; d < 64; d <<= 1) {
                const int t = __shfl_up(incl, d, 64);
                if (lane >= d) incl += t;
            }
            const int deg = __shfl(incl, 63, 64);

            if (deg == 0) {
                // all-masked row: attention = 1/n uniform -> mean of V
                float s0 = 0.f, s1 = 0.f;
                for (int m = 0; m < NN; m++) {
                    s0 += V[m * C + lane];
                    s1 += V[m * C + 64 + lane];
                }
                attn[n * C + lane]      = s0 * (1.f / (float)NN);
                attn[n * C + 64 + lane] = s1 * (1.f / (float)NN);
                continue;
            }

            const bool uselist = (deg <= LCAP);
            if (uselist) {
                int o = incl - myc;
                const int base0 = lane * 64;
                unsigned int t0 = b0;
                while (t0) { const int b = __ffs(t0) - 1; t0 &= t0 - 1; nb[o++] = (unsigned short)(base0 + b); }
                unsigned int t1 = b1;
                while (t1) { const int b = __ffs(t1) - 1; t1 &= t1 - 1; nb[o++] = (unsigned short)(base0 + 32 + b); }
            }
            // make list visible to the other lanes of this wave
            asm volatile("s_waitcnt lgkmcnt(0)" ::: "memory");

            // Q fragment for this head
            float qh[16];
            {
                const float4* qp = reinterpret_cast<const float4*>(Q + n * C + h * HD);
                const float4 q0 = qp[0], q1 = qp[1], q2 = qp[2], q3 = qp[3];
                qh[0]=q0.x; qh[1]=q0.y; qh[2]=q0.z; qh[3]=q0.w;
                qh[4]=q1.x; qh[5]=q1.y; qh[6]=q1.z; qh[7]=q1.w;
                qh[8]=q2.x; qh[9]=q2.y; qh[10]=q2.z; qh[11]=q2.w;
                qh[12]=q3.x; qh[13]=q3.y; qh[14]=q3.z; qh[15]=q3.w;
            }
            const bool cached = (deg <= SCAP);

            // ---- pass 1: scores (+ cache) + max ----
            float mmax = -INFINITY;
            if (uselist) {
                for (int i = sub; i < deg; i += 8) {
                    const float s = dot16(qh, K + nb[i] * C + h * HD) * 0.25f;
                    if (cached) sc[i * 8 + h] = s;
                    mmax = fmaxf(mmax, s);
                }
            } else {
                for (int m = sub; m < NN; m += 8)
                    if ((row[m >> 5] >> (m & 31)) & 1u)
                        mmax = fmaxf(mmax, dot16(qh, K + m * C + h * HD) * 0.25f);
            }
            #pragma unroll
            for (int o = 8; o < 64; o <<= 1)
                mmax = fmaxf(mmax, __shfl_xor(mmax, o, 64));

            // ---- pass 2: sum of exp ----
            float ssum = 0.f;
            if (cached) {
                for (int i = sub; i < deg; i += 8)
                    ssum += __expf(sc[i * 8 + h] - mmax);
            } else if (uselist) {
                for (int i = sub; i < deg; i += 8)
                    ssum += __expf(dot16(qh, K + nb[i] * C + h * HD) * 0.25f - mmax);
            } else {
                for (int m = sub; m < NN; m += 8)
                    if ((row[m >> 5] >> (m & 31)) & 1u)
                        ssum += __expf(dot16(qh, K + m * C + h * HD) * 0.25f - mmax);
            }
            #pragma unroll
            for (int o = 8; o < 64; o <<= 1)
                ssum += __shfl_xor(ssum, o, 64);
            const float inv = 1.f / ssum;

            // ---- pass 3: P @ V ----
            float acc[16];
            #pragma unroll
            for (int d = 0; d < 16; d++) acc[d] = 0.f;
            if (cached) {
                for (int i = sub; i < deg; i += 8) {
                    const float p = __expf(sc[i * 8 + h] - mmax) * inv;
                    pv16(p, V + nb[i] * C + h * HD, acc);
                }
            } else if (uselist) {
                for (int i = sub; i < deg; i += 8) {
                    const float p = __expf(dot16(qh, K + nb[i] * C + h * HD) * 0.25f - mmax) * inv;
                    pv16(p, V + nb[i] * C + h * HD, acc);
                }
            } else {
                for (int m = sub; m < NN; m += 8) {
                    if ((row[m >> 5] >> (m & 31)) & 1u) {
                        const float p = __expf(dot16(qh, K + m * C + h * HD) * 0.25f - mmax) * inv;
                        pv16(p, V + m * C + h * HD, acc);
                    }
                }
            }
            #pragma unroll
            for (int o = 8; o < 64; o <<= 1) {
                #pragma unroll
                for (int d = 0; d < 16; d++)
                    acc[d] += __shfl_xor(acc[d], o, 64);
            }
            if (sub == 0) {
                float4* op = reinterpret_cast<float4*>(attn + n * C + h * HD);
                op[0] = make_float4(acc[0],  acc[1],  acc[2],  acc[3]);
                op[1] = make_float4(acc[4],  acc[5],  acc[6],  acc[7]);
                op[2] = make_float4(acc[8],  acc[9],  acc[10], acc[11]);
                op[3] = make_float4(acc[12], acc[13], acc[14], acc[15]);
            }
        }
    }
    grid.sync();

    // ---------------- phase 3: output projection ----------------
    {
        const int n0 = blk * NPB;
        for (int i = tid; i < NPB * C; i += 256)
            sh.xs[i >> 7][i & 127] = attn[n0 * C + i];
        __syncthreads();

        const int c = tid & 127;
        const int half = tid >> 7;
        float ac[4];
        #pragma unroll
        for (int j = 0; j < 4; j++) ac[j] = 0.f;
        for (int k = 0; k < C; k++) {
            const float wo = Wo[k * C + c];
            #pragma unroll
            for (int j = 0; j < 4; j++)
                ac[j] = fmaf(sh.xs[half * 4 + j][k], wo, ac[j]);
        }
        const float bov = bo[c];
        #pragma unroll
        for (int j = 0; j < 4; j++)
            out[(n0 + half * 4 + j) * C + c] = ac[j] + bov;
    }
}

extern "C" void kernel_launch(void* const* d_in, const int* in_sizes, int n_in,
                              void* d_out, int out_size, void* d_ws, size_t ws_size,
                              hipStream_t stream)
{
    const float* x  = (const float*)d_in[0];
    const int*   ei = (const int*)d_in[1];
    const float* Wq = (const float*)d_in[2];
    const float* bq = (const float*)d_in[3];
    const float* Wk = (const float*)d_in[4];
    const float* bk = (const float*)d_in[5];
    const float* Wv = (const float*)d_in[6];
    const float* bv = (const float*)d_in[7];
    const float* Wo = (const float*)d_in[8];
    const float* bo = (const float*)d_in[9];
    float* out = (float*)d_out;
    char* ws = (char*)d_ws;

    void* args[12] = {
        (void*)&x, (void*)&ei, (void*)&Wq, (void*)&bq, (void*)&Wk, (void*)&bk,
        (void*)&Wv, (void*)&bv, (void*)&Wo, (void*)&bo, (void*)&ws, (void*)&out
    };
    hipLaunchCooperativeKernel((const void*)gat_fused, dim3(NBLK), dim3(256),
                               args, 0, stream);
}

// Round 4
// 60.833 us; speedup vs baseline: 3.7587x; 3.7587x over previous
//
#include <hip/hip_runtime.h>
#include <math.h>

#define NN 4096
#define NE 131072
#define C 128
#define NH 8
#define HD 16
#define DCAP 128     // per-node neighbor capacity (binomial mean 32, max ~60)

__device__ __forceinline__ float dot16(const float* __restrict__ q, const float* __restrict__ kp) {
    const float4* k4 = reinterpret_cast<const float4*>(kp);
    const float4 k0 = k4[0], k1 = k4[1], k2 = k4[2], k3 = k4[3];
    return q[0]*k0.x + q[1]*k0.y + q[2]*k0.z + q[3]*k0.w
         + q[4]*k1.x + q[5]*k1.y + q[6]*k1.z + q[7]*k1.w
         + q[8]*k2.x + q[9]*k2.y + q[10]*k2.z + q[11]*k2.w
         + q[12]*k3.x + q[13]*k3.y + q[14]*k3.z + q[15]*k3.w;
}

// ------- K1: QKV projection + clear mask/deg (512 blocks x 256) -------
__global__ __launch_bounds__(256) void qkv_kernel(
    const float* __restrict__ x,
    const float* __restrict__ Wq, const float* __restrict__ bq,
    const float* __restrict__ Wk, const float* __restrict__ bk,
    const float* __restrict__ Wv, const float* __restrict__ bv,
    float* __restrict__ Q, float* __restrict__ K, float* __restrict__ V,
    float4* __restrict__ mask_clear, int* __restrict__ deg)
{
    // clear 2 MiB mask: 512*256 threads x 16B
    mask_clear[blockIdx.x * 256 + threadIdx.x] = make_float4(0.f, 0.f, 0.f, 0.f);
    // clear 16 KiB deg
    if (threadIdx.x < 8) deg[blockIdx.x * 8 + threadIdx.x] = 0;

    __shared__ float xs[8][C];
    const int n0 = blockIdx.x * 8;
    for (int i = threadIdx.x; i < 8 * C; i += 256)
        xs[i >> 7][i & 127] = x[n0 * C + i];
    __syncthreads();

    const int c = threadIdx.x & 127;
    const int half = threadIdx.x >> 7;     // nodes half*4 .. +4
    float aq[4], ak[4], av[4];
    #pragma unroll
    for (int j = 0; j < 4; j++) { aq[j] = 0.f; ak[j] = 0.f; av[j] = 0.f; }
    for (int k = 0; k < C; k++) {
        const float wq = Wq[k * C + c];
        const float wk = Wk[k * C + c];
        const float wv = Wv[k * C + c];
        #pragma unroll
        for (int j = 0; j < 4; j++) {
            const float xv = xs[half * 4 + j][k];
            aq[j] = fmaf(xv, wq, aq[j]);
            ak[j] = fmaf(xv, wk, ak[j]);
            av[j] = fmaf(xv, wv, av[j]);
        }
    }
    const float bqv = bq[c], bkv = bk[c], bvv = bv[c];
    #pragma unroll
    for (int j = 0; j < 4; j++) {
        const int n = n0 + half * 4 + j;
        Q[n * C + c] = aq[j] + bqv;
        K[n * C + c] = ak[j] + bkv;
        V[n * C + c] = av[j] + bvv;
    }
}

// ------- K2: edge scatter -> dedup bitmask + compact adjacency lists -------
__global__ __launch_bounds__(256) void scatter_kernel(
    const int* __restrict__ ei, unsigned int* __restrict__ mask,
    int* __restrict__ deg, int* __restrict__ nbr)
{
    const int e = blockIdx.x * 256 + threadIdx.x;
    int src = ei[e];
    int dst = ei[NE + e];
    src = src < 0 ? 0 : (src > NN - 1 ? NN - 1 : src);
    dst = dst < 0 ? 0 : (dst > NN - 1 ? NN - 1 : dst);
    const unsigned int bit = 1u << (dst & 31);
    const unsigned int old = atomicOr(&mask[(src << 7) + (dst >> 5)], bit);
    if (!(old & bit)) {
        const int p = atomicAdd(&deg[src], 1);
        if (p < DCAP) nbr[(src << 7) + p] = dst;
    }
}

// ------- K3: sparse attention (1 wave/node, online softmax) + output proj -------
// 1024 blocks x 256 threads: wave w of block b handles node b*4+w.
__global__ __launch_bounds__(256) void attn_proj_kernel(
    const float* __restrict__ Q, const float* __restrict__ K,
    const float* __restrict__ V, const int* __restrict__ deg,
    const int* __restrict__ nbr, const float* __restrict__ Wo,
    const float* __restrict__ bo, float* __restrict__ out)
{
    __shared__ float row[4][C];
    const int tid = threadIdx.x;
    const int w = tid >> 6;
    const int lane = tid & 63;
    const int n = blockIdx.x * 4 + w;
    const int h = lane & 7;           // head: 8 lanes of a sub-group cover 8 heads
    const int sub = lane >> 3;        // 8 sub-lanes per head

    const int dg = deg[n];

    // Q fragment for this head
    float qh[16];
    {
        const float4* qp = reinterpret_cast<const float4*>(Q + n * C + h * HD);
        const float4 q0 = qp[0], q1 = qp[1], q2 = qp[2], q3 = qp[3];
        qh[0]=q0.x; qh[1]=q0.y; qh[2]=q0.z; qh[3]=q0.w;
        qh[4]=q1.x; qh[5]=q1.y; qh[6]=q1.z; qh[7]=q1.w;
        qh[8]=q2.x; qh[9]=q2.y; qh[10]=q2.z; qh[11]=q2.w;
        qh[12]=q3.x; qh[13]=q3.y; qh[14]=q3.z; qh[15]=q3.w;
    }

    float mloc = -INFINITY, ssum = 0.f;
    float acc[16];
    #pragma unroll
    for (int d = 0; d < 16; d++) acc[d] = 0.f;

    if (dg > 0) {
        const int* lst = nbr + (n << 7);
        for (int i = sub; i < dg; i += 8) {
            const int m = lst[i];
            const float sc = dot16(qh, K + m * C + h * HD) * 0.25f;
            const float nm = fmaxf(mloc, sc);
            const float scale = __expf(mloc - nm);   // first iter: exp(-inf)=0
            const float p = __expf(sc - nm);
            ssum = ssum * scale + p;
            const float4* v4 = reinterpret_cast<const float4*>(V + m * C + h * HD);
            const float4 v0 = v4[0], v1 = v4[1], v2 = v4[2], v3 = v4[3];
            acc[0]  = fmaf(p, v0.x, acc[0]  * scale);
            acc[1]  = fmaf(p, v0.y, acc[1]  * scale);
            acc[2]  = fmaf(p, v0.z, acc[2]  * scale);
            acc[3]  = fmaf(p, v0.w, acc[3]  * scale);
            acc[4]  = fmaf(p, v1.x, acc[4]  * scale);
            acc[5]  = fmaf(p, v1.y, acc[5]  * scale);
            acc[6]  = fmaf(p, v1.z, acc[6]  * scale);
            acc[7]  = fmaf(p, v1.w, acc[7]  * scale);
            acc[8]  = fmaf(p, v2.x, acc[8]  * scale);
            acc[9]  = fmaf(p, v2.y, acc[9]  * scale);
            acc[10] = fmaf(p, v2.z, acc[10] * scale);
            acc[11] = fmaf(p, v2.w, acc[11] * scale);
            acc[12] = fmaf(p, v3.x, acc[12] * scale);
            acc[13] = fmaf(p, v3.y, acc[13] * scale);
            acc[14] = fmaf(p, v3.z, acc[14] * scale);
            acc[15] = fmaf(p, v3.w, acc[15] * scale);
            mloc = nm;
        }
        // merge the 8 sub-lane online states of each head
        float M = mloc;
        #pragma unroll
        for (int o = 8; o < 64; o <<= 1)
            M = fmaxf(M, __shfl_xor(M, o, 64));
        const float f = __expf(mloc - M);            // empty sub-lane: exp(-inf)=0
        ssum *= f;
        #pragma unroll
        for (int d = 0; d < 16; d++) acc[d] *= f;
        #pragma unroll
        for (int o = 8; o < 64; o <<= 1)
            ssum += __shfl_xor(ssum, o, 64);
        #pragma unroll
        for (int o = 8; o < 64; o <<= 1) {
            #pragma unroll
            for (int d = 0; d < 16; d++)
                acc[d] += __shfl_xor(acc[d], o, 64);
        }
        const float inv = 1.f / ssum;
        if (sub == 0) {
            float4* rp = reinterpret_cast<float4*>(&row[w][h * HD]);
            rp[0] = make_float4(acc[0]*inv,  acc[1]*inv,  acc[2]*inv,  acc[3]*inv);
            rp[1] = make_float4(acc[4]*inv,  acc[5]*inv,  acc[6]*inv,  acc[7]*inv);
            rp[2] = make_float4(acc[8]*inv,  acc[9]*inv,  acc[10]*inv, acc[11]*inv);
            rp[3] = make_float4(acc[12]*inv, acc[13]*inv, acc[14]*inv, acc[15]*inv);
        }
    } else {
        // all-masked row: attention = 1/n uniform -> mean of V per channel
        for (int d = lane; d < C; d += 64) {
            float s = 0.f;
            for (int m = 0; m < NN; m++) s += V[m * C + d];
            row[w][d] = s * (1.f / (float)NN);
        }
    }
    __syncthreads();

    // output projection: out[n] = row[n] @ Wo + bo  (4 nodes, 512 outputs, 256 thr)
    const int c = tid & 127;
    const int r = tid >> 7;           // 0..1 -> nodes {r, r+2}
    float a0 = 0.f, a1 = 0.f;
    for (int k = 0; k < C; k++) {
        const float wo = Wo[k * C + c];
        a0 = fmaf(row[r][k],     wo, a0);
        a1 = fmaf(row[r + 2][k], wo, a1);
    }
    const float bov = bo[c];
    out[(blockIdx.x * 4 + r) * C + c]     = a0 + bov;
    out[(blockIdx.x * 4 + r + 2) * C + c] = a1 + bov;
}

extern "C" void kernel_launch(void* const* d_in, const int* in_sizes, int n_in,
                              void* d_out, int out_size, void* d_ws, size_t ws_size,
                              hipStream_t stream)
{
    const float* x  = (const float*)d_in[0];
    const int*   ei = (const int*)d_in[1];
    const float* Wq = (const float*)d_in[2];
    const float* bq = (const float*)d_in[3];
    const float* Wk = (const float*)d_in[4];
    const float* bk = (const float*)d_in[5];
    const float* Wv = (const float*)d_in[6];
    const float* bv = (const float*)d_in[7];
    const float* Wo = (const float*)d_in[8];
    const float* bo = (const float*)d_in[9];
    float* out = (float*)d_out;

    char* ws = (char*)d_ws;
    const size_t MB2 = 1u << 21;
    float*        Q    = (float*)(ws);
    float*        K    = (float*)(ws + MB2);
    float*        V    = (float*)(ws + 2 * MB2);
    unsigned int* mask = (unsigned int*)(ws + 3 * MB2);
    int*          nbr  = (int*)(ws + 4 * MB2);          // 4096*128*4 = 2 MiB
    int*          deg  = (int*)(ws + 5 * MB2);          // 16 KiB

    qkv_kernel<<<512, 256, 0, stream>>>(x, Wq, bq, Wk, bk, Wv, bv, Q, K, V,
                                        (float4*)mask, deg);
    scatter_kernel<<<NE / 256, 256, 0, stream>>>(ei, mask, deg, nbr);
    attn_proj_kernel<<<NN / 4, 256, 0, stream>>>(Q, K, V, deg, nbr, Wo, bo, out);
}